// Round 1
// baseline (1760.215 us; speedup 1.0000x reference)
//
#include <hip/hip_runtime.h>

namespace {
constexpr int kN = 32;
constexpr int kCin = 240;
constexpr int kW = 56;
constexpr int kHW = 56 * 56;   // 3136
constexpr int kMid = 120;
constexpr int kG = 3;
constexpr int kCinG = 80;      // Cin / G
constexpr int kMidG = 40;      // mid / G
constexpr int kCout = 480;
constexpr int kCoutG = 160;    // Cout / G
constexpr int kTiles = 13;     // ceil(3136 / 256)
constexpr int kCb = kCout / kMidG;  // 12 output-channel blocks in kernel 3
}  // namespace

// ---------------- kernel 1: grouped 1x1 conv (240->120, G=3) + BN + ReLU ----
__global__ __launch_bounds__(256) void conv1_bn_relu(
    const float* __restrict__ x, const float* __restrict__ w1,
    const float* __restrict__ scale1, const float* __restrict__ shift1,
    float* __restrict__ y1) {
  const int tile = blockIdx.x % kTiles;
  const int g = (blockIdx.x / kTiles) % kG;
  const int n = blockIdx.x / (kTiles * kG);
  const int p = tile * 256 + threadIdx.x;
  if (p >= kHW) return;

  float acc[kMidG];
#pragma unroll
  for (int j = 0; j < kMidG; ++j) acc[j] = 0.f;

  const float* xp = x + ((size_t)n * kCin + g * kCinG) * kHW + p;
  const float* wp = w1 + (size_t)(g * kMidG) * kCinG;  // w1[g*40 + j][k]

  for (int k = 0; k < kCinG; k += 4) {
    const float x0 = xp[(size_t)(k + 0) * kHW];
    const float x1 = xp[(size_t)(k + 1) * kHW];
    const float x2 = xp[(size_t)(k + 2) * kHW];
    const float x3 = xp[(size_t)(k + 3) * kHW];
#pragma unroll
    for (int j = 0; j < kMidG; ++j) {
      const float* w4 = wp + j * kCinG + k;  // wave-uniform -> scalar loads
      acc[j] = fmaf(w4[0], x0, acc[j]);
      acc[j] = fmaf(w4[1], x1, acc[j]);
      acc[j] = fmaf(w4[2], x2, acc[j]);
      acc[j] = fmaf(w4[3], x3, acc[j]);
    }
  }

  float* yp = y1 + ((size_t)n * kMid + g * kMidG) * kHW + p;
#pragma unroll
  for (int j = 0; j < kMidG; ++j) {
    const int c = g * kMidG + j;
    float v = fmaf(acc[j], scale1[c], shift1[c]);
    yp[(size_t)j * kHW] = v > 0.f ? v : 0.f;
  }
}

// ------- kernel 2: depthwise 3x3 (pad 1) + BN2, written channel-shuffled ----
__global__ __launch_bounds__(256) void dw3x3_bn_shuffle(
    const float* __restrict__ y1, const float* __restrict__ w2,
    const float* __restrict__ scale2, const float* __restrict__ shift2,
    float* __restrict__ y2s) {
  const int tile = blockIdx.x % kTiles;
  const int c = (blockIdx.x / kTiles) % kMid;
  const int n = blockIdx.x / (kTiles * kMid);
  const int p = tile * 256 + threadIdx.x;
  if (p >= kHW) return;
  const int h = p / kW;
  const int w = p % kW;

  const float* ip = y1 + ((size_t)n * kMid + c) * kHW;
  float acc = 0.f;
#pragma unroll
  for (int dy = 0; dy < 3; ++dy) {
    const int hh = h + dy - 1;
    if (hh < 0 || hh >= kW) continue;
#pragma unroll
    for (int dx = 0; dx < 3; ++dx) {
      const int ww = w + dx - 1;
      if (ww < 0 || ww >= kW) continue;
      acc = fmaf(ip[hh * kW + ww], w2[c * 9 + dy * 3 + dx], acc);
    }
  }
  const float v = fmaf(acc, scale2[c], shift2[c]);
  // channel shuffle g=3: orig c = gi*40+ci -> new channel ci*3+gi
  const int cn = (c % kMidG) * kG + c / kMidG;
  y2s[((size_t)n * kMid + cn) * kHW + p] = v;
}

// -- kernel 3: grouped 1x1 (120->480) + BN3 + ReLU + shortcut 1x1 + BN_sc ----
__global__ __launch_bounds__(256) void conv3_sc_fuse(
    const float* __restrict__ x, const float* __restrict__ y2s,
    const float* __restrict__ w3, const float* __restrict__ scale3,
    const float* __restrict__ shift3, const float* __restrict__ wsc,
    const float* __restrict__ scale_sc, const float* __restrict__ shift_sc,
    float* __restrict__ out) {
  const int tile = blockIdx.x % kTiles;
  const int cb = (blockIdx.x / kTiles) % kCb;
  const int n = blockIdx.x / (kTiles * kCb);
  const int p = tile * 256 + threadIdx.x;
  if (p >= kHW) return;
  const int co0 = cb * kMidG;        // 40 output channels, within one group
  const int go = co0 / kCoutG;       // conv3 group index

  // ---- shortcut: 1x1 conv over all 240 input channels ----
  float accs[kMidG];
#pragma unroll
  for (int j = 0; j < kMidG; ++j) accs[j] = 0.f;
  const float* xp = x + (size_t)n * kCin * kHW + p;
  for (int k = 0; k < kCin; k += 4) {
    const float x0 = xp[(size_t)(k + 0) * kHW];
    const float x1 = xp[(size_t)(k + 1) * kHW];
    const float x2 = xp[(size_t)(k + 2) * kHW];
    const float x3 = xp[(size_t)(k + 3) * kHW];
#pragma unroll
    for (int j = 0; j < kMidG; ++j) {
      const float* w4 = wsc + (size_t)(co0 + j) * kCin + k;
      accs[j] = fmaf(w4[0], x0, accs[j]);
      accs[j] = fmaf(w4[1], x1, accs[j]);
      accs[j] = fmaf(w4[2], x2, accs[j]);
      accs[j] = fmaf(w4[3], x3, accs[j]);
    }
  }
#pragma unroll
  for (int j = 0; j < kMidG; ++j)
    accs[j] = fmaf(accs[j], scale_sc[co0 + j], shift_sc[co0 + j]);

  // ---- conv3: 40 shuffled mid channels of this group ----
  float acc3[kMidG];
#pragma unroll
  for (int j = 0; j < kMidG; ++j) acc3[j] = 0.f;
  const float* yp = y2s + ((size_t)n * kMid + go * kMidG) * kHW + p;
  for (int k = 0; k < kMidG; k += 4) {
    const float y0 = yp[(size_t)(k + 0) * kHW];
    const float y1v = yp[(size_t)(k + 1) * kHW];
    const float y2v = yp[(size_t)(k + 2) * kHW];
    const float y3v = yp[(size_t)(k + 3) * kHW];
#pragma unroll
    for (int j = 0; j < kMidG; ++j) {
      const float* w4 = w3 + (size_t)(co0 + j) * kMidG + k;
      acc3[j] = fmaf(w4[0], y0, acc3[j]);
      acc3[j] = fmaf(w4[1], y1v, acc3[j]);
      acc3[j] = fmaf(w4[2], y2v, acc3[j]);
      acc3[j] = fmaf(w4[3], y3v, acc3[j]);
    }
  }

  float* op = out + ((size_t)n * kCout + co0) * kHW + p;
#pragma unroll
  for (int j = 0; j < kMidG; ++j) {
    float v = fmaf(acc3[j], scale3[co0 + j], shift3[co0 + j]);
    v = v > 0.f ? v : 0.f;
    op[(size_t)j * kHW] = v + accs[j];
  }
}

extern "C" void kernel_launch(void* const* d_in, const int* in_sizes, int n_in,
                              void* d_out, int out_size, void* d_ws,
                              size_t ws_size, hipStream_t stream) {
  const float* x = (const float*)d_in[0];
  const float* w1 = (const float*)d_in[1];
  const float* scale1 = (const float*)d_in[2];
  const float* shift1 = (const float*)d_in[3];
  const float* w2 = (const float*)d_in[4];
  const float* scale2 = (const float*)d_in[5];
  const float* shift2 = (const float*)d_in[6];
  const float* w3 = (const float*)d_in[7];
  const float* scale3 = (const float*)d_in[8];
  const float* shift3 = (const float*)d_in[9];
  const float* wsc = (const float*)d_in[10];
  const float* ssc = (const float*)d_in[11];
  const float* bsc = (const float*)d_in[12];
  // d_in[13] = groups (int, ==3) -- hardcoded in kernels
  float* out = (float*)d_out;

  float* y1 = (float*)d_ws;                       // 32*120*3136 floats
  float* y2s = y1 + (size_t)kN * kMid * kHW;      // shuffled dw output

  conv1_bn_relu<<<kN * kG * kTiles, 256, 0, stream>>>(x, w1, scale1, shift1,
                                                      y1);
  dw3x3_bn_shuffle<<<kN * kMid * kTiles, 256, 0, stream>>>(y1, w2, scale2,
                                                           shift2, y2s);
  conv3_sc_fuse<<<kN * kCb * kTiles, 256, 0, stream>>>(
      x, y2s, w3, scale3, shift3, wsc, ssc, bsc, out);
}

// Round 2
// 533.089 us; speedup vs baseline: 3.3019x; 3.3019x over previous
//
#include <hip/hip_runtime.h>

typedef short bf16x8 __attribute__((ext_vector_type(8)));
typedef float f32x4 __attribute__((ext_vector_type(4)));

namespace {
constexpr int kN = 32;
constexpr int kCin = 240;
constexpr int kHW = 3136;
constexpr int kMid = 120;
constexpr int kCout = 480;
// workspace layout (bytes) -- total 96,337,920 (same as round-1's proven usage)
// order matters: k-dim overruns in the GEMMs read a few elements past each
// buffer; the next buffer must be in-bounds, finite memory.
constexpr size_t kXbtBytes = (size_t)kN * kHW * 240 * 2;  // 48,168,960
constexpr size_t kY2Off = kXbtBytes;                      // y2t after xbt
constexpr size_t kY2Bytes = (size_t)kN * kHW * 120 * 2;   // 24,084,480
constexpr size_t kY1Off = kY2Off + kY2Bytes;              // y1b last
}  // namespace

// bf16 weights, zero-padded along k to a multiple of 32 (so every MFMA k-step
// is a full K=32; A-side overrun garbage is multiplied by B-side zeros).
__device__ __align__(16) unsigned short g_w1b[3 * 48 * 96];   // [g][j<48][c<96]
__device__ __align__(16) unsigned short g_wscb[480 * 256];    // [co][c<256]
__device__ __align__(16) unsigned short g_w3b[480 * 64];      // [co][s<64]

static __device__ __forceinline__ unsigned short f2b(float f) {
  unsigned u = __float_as_uint(f);
  u = (u + 0x7fffu + ((u >> 16) & 1u)) >> 16;  // RNE
  return (unsigned short)u;
}
static __device__ __forceinline__ float b2f(unsigned short s) {
  return __uint_as_float(((unsigned)s) << 16);
}
static __device__ __forceinline__ f32x4 mfma16(bf16x8 a, bf16x8 b, f32x4 c) {
  return __builtin_amdgcn_mfma_f32_16x16x32_bf16(a, b, c, 0, 0, 0);
}

// ---------------- weight prep: fp32 -> padded bf16 ----------------
__global__ __launch_bounds__(256) void prep_weights(
    const float* __restrict__ w1, const float* __restrict__ wsc,
    const float* __restrict__ w3) {
  const int idx = blockIdx.x * 256 + threadIdx.x;
  if (idx < 3 * 48 * 96) {
    const int g = idx / (48 * 96), r = idx % (48 * 96), j = r / 96, c = r % 96;
    g_w1b[idx] =
        (j < 40 && c < 80) ? f2b(w1[(g * 40 + j) * 80 + c]) : (unsigned short)0;
  } else if (idx < 3 * 48 * 96 + 480 * 256) {
    const int i = idx - 3 * 48 * 96;
    const int co = i >> 8, c = i & 255;
    g_wscb[i] = (c < 240) ? f2b(wsc[co * 240 + c]) : (unsigned short)0;
  } else if (idx < 3 * 48 * 96 + 480 * 256 + 480 * 64) {
    const int i = idx - (3 * 48 * 96 + 480 * 256);
    const int co = i >> 6, s = i & 63;
    g_w3b[i] = (s < 40) ? f2b(w3[co * 40 + s]) : (unsigned short)0;
  }
}

// ------------- transpose + cast: x[n][c][p] f32 -> xbt[n*HW+p][240] bf16 ----
__global__ __launch_bounds__(256) void transpose_cast_x(
    const float* __restrict__ x, unsigned short* __restrict__ xbt) {
  const int pt = blockIdx.x % 13;
  const int ct = (blockIdx.x / 13) % 15;
  const int n = blockIdx.x / (13 * 15);
  const int p = pt * 256 + threadIdx.x;
  if (p >= kHW) return;
  const float* xp = x + ((size_t)n * kCin + ct * 16) * kHW + p;
  unsigned short v[16];
#pragma unroll
  for (int r = 0; r < 16; ++r) v[r] = f2b(xp[(size_t)r * kHW]);
  unsigned short* dst = xbt + (size_t)(n * kHW + p) * 240 + ct * 16;
  *reinterpret_cast<int4*>(dst) = *reinterpret_cast<const int4*>(v);
  *reinterpret_cast<int4*>(dst + 8) = *reinterpret_cast<const int4*>(v + 8);
}

// ---- conv1 (grouped 1x1, K=80) as MFMA GEMM + BN + ReLU -> y1b[n][c][p] ----
__global__ __launch_bounds__(256) void conv1_gemm(
    const unsigned short* __restrict__ xbt, const float* __restrict__ scale1,
    const float* __restrict__ shift1, unsigned short* __restrict__ y1b) {
  const int pt = blockIdx.x % 49;
  const int g = (blockIdx.x / 49) % 3;
  const int n = blockIdx.x / (49 * 3);
  const int P0 = pt * 64;
  const int lane = threadIdx.x & 63;
  const int wv = threadIdx.x >> 6;  // 4 waves, each owns 16 pixels
  const int l15 = lane & 15, quad = lane >> 4;

  f32x4 acc[3];
#pragma unroll
  for (int nt = 0; nt < 3; ++nt) acc[nt] = (f32x4){0.f, 0.f, 0.f, 0.f};

  const unsigned short* abase =
      xbt + (size_t)(n * kHW + P0 + wv * 16 + l15) * 240 + g * 80 + quad * 8;
  const unsigned short* bbase = g_w1b + (g * 48 + l15) * 96 + quad * 8;
#pragma unroll
  for (int ks = 0; ks < 3; ++ks) {  // K = 96 (80 real + 16 zero-weight)
    const bf16x8 a = *reinterpret_cast<const bf16x8*>(abase + ks * 32);
#pragma unroll
    for (int nt = 0; nt < 3; ++nt) {
      const bf16x8 b =
          *reinterpret_cast<const bf16x8*>(bbase + nt * 16 * 96 + ks * 32);
      acc[nt] = mfma16(a, b, acc[nt]);
    }
  }

  __shared__ unsigned short lds[48 * 72];
#pragma unroll
  for (int nt = 0; nt < 3; ++nt) {
    const int j = nt * 16 + l15;
    if (j < 40) {
      const int c = g * 40 + j;
      const float sc = scale1[c], sh = shift1[c];
#pragma unroll
      for (int r = 0; r < 4; ++r) {
        float v = fmaf(acc[nt][r], sc, sh);
        v = v > 0.f ? v : 0.f;
        lds[j * 72 + wv * 16 + quad * 4 + r] = f2b(v);
      }
    }
  }
  __syncthreads();
  unsigned short* yb = y1b + ((size_t)n * kMid + g * 40) * kHW;
#pragma unroll
  for (int i = 0; i < 10; ++i) {  // 40 ch x 64 px = 2560 = 10*256
    const int e = threadIdx.x + i * 256;
    const int c = e >> 6, pp = e & 63;
    yb[(size_t)c * kHW + P0 + pp] = lds[c * 72 + pp];
  }
}

// - depthwise 3x3 + BN2, written shuffled AND transposed: y2t[n*HW+p][120] ---
__global__ __launch_bounds__(256) void dw_bn_shuffle(
    const unsigned short* __restrict__ y1b, const float* __restrict__ w2,
    const float* __restrict__ scale2, const float* __restrict__ shift2,
    unsigned short* __restrict__ y2t) {
  const int h = blockIdx.x % 56;
  const int n = blockIdx.x / 56;
  __shared__ unsigned short lds[120 * 58];
  const unsigned short* yb = y1b + (size_t)n * kMid * kHW;
  for (int idx = threadIdx.x; idx < 120 * 56; idx += 256) {
    const int c = idx / 56, w = idx % 56;
    float acc = 0.f;
    const unsigned short* ip = yb + (size_t)c * kHW;
    const float* wp = w2 + c * 9;
#pragma unroll
    for (int dy = 0; dy < 3; ++dy) {
      const int hh = h + dy - 1;
      if (hh < 0 || hh >= 56) continue;
#pragma unroll
      for (int dx = 0; dx < 3; ++dx) {
        const int ww = w + dx - 1;
        if (ww < 0 || ww >= 56) continue;
        acc = fmaf(b2f(ip[hh * 56 + ww]), wp[dy * 3 + dx], acc);
      }
    }
    const float v = fmaf(acc, scale2[c], shift2[c]);
    // shuffle g=3: c = gi*40+ci -> cn = ci*3+gi
    const int cn = (c % 40) * 3 + c / 40;
    lds[cn * 58 + w] = f2b(v);
  }
  __syncthreads();
  unsigned short* dst = y2t + (size_t)(n * kHW + h * 56) * 120;
  for (int e = threadIdx.x; e < 56 * 120; e += 256)
    dst[e] = lds[(e % 120) * 58 + (e / 120)];
}

// ----- fused: conv3 GEMM (K=40) + BN3 + ReLU + shortcut GEMM (K=240) + BN ---
__global__ __launch_bounds__(256) void conv3_sc_gemm(
    const unsigned short* __restrict__ xbt,
    const unsigned short* __restrict__ y2t, const float* __restrict__ scale3,
    const float* __restrict__ shift3, const float* __restrict__ ssc,
    const float* __restrict__ bsc, float* __restrict__ out) {
  const int pt = blockIdx.x % 49;
  const int cb = (blockIdx.x / 49) % 3;  // co block of 160 == conv3 group
  const int n = blockIdx.x / (49 * 3);
  const int P0 = pt * 64;
  const int lane = threadIdx.x & 63;
  const int wv = threadIdx.x >> 6;
  const int mh = wv & 1, nh = wv >> 1;  // wave tile: 32 px x 80 co
  const int l15 = lane & 15, quad = lane >> 4;

  f32x4 acc_sc[2][5], acc_c3[2][5];
#pragma unroll
  for (int ms = 0; ms < 2; ++ms)
#pragma unroll
    for (int nt = 0; nt < 5; ++nt) {
      acc_sc[ms][nt] = (f32x4){0.f, 0.f, 0.f, 0.f};
      acc_c3[ms][nt] = (f32x4){0.f, 0.f, 0.f, 0.f};
    }

  const int co_row = cb * 160 + nh * 80 + l15;
  // ---- shortcut GEMM: K = 256 (240 real + 16 zero-weight) ----
  {
    const size_t prow = (size_t)(n * kHW + P0 + mh * 32 + l15) * 240;
    const unsigned short* a0 = xbt + prow + quad * 8;
    const unsigned short* a1 = xbt + prow + 16 * 240 + quad * 8;
    const unsigned short* b0 = g_wscb + co_row * 256 + quad * 8;
#pragma unroll
    for (int ks = 0; ks < 8; ++ks) {
      const bf16x8 A0 = *reinterpret_cast<const bf16x8*>(a0 + ks * 32);
      const bf16x8 A1 = *reinterpret_cast<const bf16x8*>(a1 + ks * 32);
#pragma unroll
      for (int nt = 0; nt < 5; ++nt) {
        const bf16x8 B =
            *reinterpret_cast<const bf16x8*>(b0 + nt * 16 * 256 + ks * 32);
        acc_sc[0][nt] = mfma16(A0, B, acc_sc[0][nt]);
        acc_sc[1][nt] = mfma16(A1, B, acc_sc[1][nt]);
      }
    }
  }
  // ---- conv3 GEMM: K = 64 (40 real + 24 zero-weight) ----
  {
    const size_t qrow = (size_t)(n * kHW + P0 + mh * 32 + l15) * 120 + cb * 40;
    const unsigned short* a0 = y2t + qrow + quad * 8;
    const unsigned short* a1 = y2t + qrow + 16 * 120 + quad * 8;
    const unsigned short* b3 = g_w3b + co_row * 64 + quad * 8;
#pragma unroll
    for (int ks = 0; ks < 2; ++ks) {
      const bf16x8 A0 = *reinterpret_cast<const bf16x8*>(a0 + ks * 32);
      const bf16x8 A1 = *reinterpret_cast<const bf16x8*>(a1 + ks * 32);
#pragma unroll
      for (int nt = 0; nt < 5; ++nt) {
        const bf16x8 B =
            *reinterpret_cast<const bf16x8*>(b3 + nt * 16 * 64 + ks * 32);
        acc_c3[0][nt] = mfma16(A0, B, acc_c3[0][nt]);
        acc_c3[1][nt] = mfma16(A1, B, acc_c3[1][nt]);
      }
    }
  }
  // ---- epilogue: relu(bn3) + bn_sc, coalesced float4 stores ----
  float* ob = out + (size_t)n * kCout * kHW;
#pragma unroll
  for (int nt = 0; nt < 5; ++nt) {
    const int co = cb * 160 + nh * 80 + nt * 16 + l15;
    const float s3 = scale3[co], h3 = shift3[co];
    const float s_ = ssc[co], h_ = bsc[co];
#pragma unroll
    for (int ms = 0; ms < 2; ++ms) {
      float4 r;
      float* op = ob + (size_t)co * kHW + P0 + mh * 32 + ms * 16 + quad * 4;
      float* rp = reinterpret_cast<float*>(&r);
#pragma unroll
      for (int r4 = 0; r4 < 4; ++r4) {
        float v3 = fmaf(acc_c3[ms][nt][r4], s3, h3);
        v3 = v3 > 0.f ? v3 : 0.f;
        rp[r4] = v3 + fmaf(acc_sc[ms][nt][r4], s_, h_);
      }
      *reinterpret_cast<float4*>(op) = r;
    }
  }
}

extern "C" void kernel_launch(void* const* d_in, const int* in_sizes, int n_in,
                              void* d_out, int out_size, void* d_ws,
                              size_t ws_size, hipStream_t stream) {
  const float* x = (const float*)d_in[0];
  const float* w1 = (const float*)d_in[1];
  const float* scale1 = (const float*)d_in[2];
  const float* shift1 = (const float*)d_in[3];
  const float* w2 = (const float*)d_in[4];
  const float* scale2 = (const float*)d_in[5];
  const float* shift2 = (const float*)d_in[6];
  const float* w3 = (const float*)d_in[7];
  const float* scale3 = (const float*)d_in[8];
  const float* shift3 = (const float*)d_in[9];
  const float* wsc = (const float*)d_in[10];
  const float* ssc = (const float*)d_in[11];
  const float* bsc = (const float*)d_in[12];
  float* out = (float*)d_out;

  unsigned short* xbt = (unsigned short*)d_ws;
  unsigned short* y2t = (unsigned short*)((char*)d_ws + kY2Off);
  unsigned short* y1b = (unsigned short*)((char*)d_ws + kY1Off);

  prep_weights<<<654, 256, 0, stream>>>(w1, wsc, w3);
  transpose_cast_x<<<32 * 15 * 13, 256, 0, stream>>>(x, xbt);
  conv1_gemm<<<32 * 3 * 49, 256, 0, stream>>>(xbt, scale1, shift1, y1b);
  dw_bn_shuffle<<<32 * 56, 256, 0, stream>>>(y1b, w2, scale2, shift2, y2t);
  conv3_sc_gemm<<<32 * 3 * 49, 256, 0, stream>>>(xbt, y2t, scale3, shift3, ssc,
                                                 bsc, out);
}

// Round 3
// 479.691 us; speedup vs baseline: 3.6695x; 1.1113x over previous
//
#include <hip/hip_runtime.h>

typedef short bf16x8 __attribute__((ext_vector_type(8)));
typedef float f32x4 __attribute__((ext_vector_type(4)));

namespace {
constexpr int kHW = 3136;
constexpr int kNPx = 32 * kHW;          // 100352 total pixels
constexpr int kPtiles = kNPx / 16;      // 6272
// xbi: [ptile][kb 0..7][l16*32k]  (K=256: 240 real + 16 zeros), 4096 shorts/ptile
// y2i: [ptile][kb 0..3][l16*32k]  (K=128: 120 real + 8 garbage*zero-w), 2048/pt
constexpr size_t kXbiShorts = (size_t)kPtiles * 4096;  // 51.38 MB
}  // namespace

// interleaved bf16 weights (zero-padded outside each real K-range)
__device__ __align__(16) unsigned short g_w1i[3 * 4 * 48 * 32];  // [g][kb][j48][k32], window 64g..64g+128
__device__ __align__(16) unsigned short g_wsci[8 * 480 * 32];    // [kb][co][k32], K=256
__device__ __align__(16) unsigned short g_w3i[2 * 480 * 32];     // [kb][co][k32], window 32*cb..+64

static __device__ __forceinline__ unsigned short f2b(float f) {
  unsigned u = __float_as_uint(f);
  u = (u + 0x7fffu + ((u >> 16) & 1u)) >> 16;  // RNE
  return (unsigned short)u;
}
static __device__ __forceinline__ f32x4 mfma16(bf16x8 a, bf16x8 b, f32x4 c) {
  return __builtin_amdgcn_mfma_f32_16x16x32_bf16(a, b, c, 0, 0, 0);
}
static __device__ __forceinline__ bf16x8 ldg8(const unsigned short* p) {
  return *reinterpret_cast<const bf16x8*>(p);
}

// ---------------- weight prep: fp32 -> interleaved padded bf16 -------------
__global__ __launch_bounds__(256) void prep_weights(
    const float* __restrict__ w1, const float* __restrict__ wsc,
    const float* __restrict__ w3) {
  const int idx = blockIdx.x * 256 + threadIdx.x;
  if (idx < 18432) {  // w1i
    const int g = idx / 6144, r = idx % 6144, kb = r / 1536;
    const int j = (r % 1536) / 32, k = r % 32;
    const int gk = g * 64 + kb * 32 + k;  // global cin-window position
    const int c = gk - g * 80;            // local cin within group
    unsigned short v = 0;
    if (j < 40 && c >= 0 && c < 80) v = f2b(w1[(g * 40 + j) * 80 + c]);
    g_w1i[idx] = v;
  } else if (idx < 18432 + 122880) {  // wsci
    const int i = idx - 18432;
    const int kb = i / 15360, co = (i % 15360) / 32, k = i % 32;
    const int c = kb * 32 + k;
    g_wsci[i] = (c < 240) ? f2b(wsc[co * 240 + c]) : (unsigned short)0;
  } else if (idx < 18432 + 122880 + 30720) {  // w3i
    const int i = idx - 141312;
    const int kb = i / 15360, co = (i % 15360) / 32, k = i % 32;
    const int cb = co / 160;
    const int s = cb * 32 + kb * 32 + k - cb * 40;  // local shuffled-ch index
    g_w3i[i] = (s >= 0 && s < 40) ? f2b(w3[co * 40 + s]) : (unsigned short)0;
  }
}

// ----- x [n][c][hw] f32 -> xbi interleaved bf16 (fully coalesced R/W) ------
__global__ __launch_bounds__(256) void transpose_interleave(
    const float* __restrict__ x, unsigned short* __restrict__ xbi) {
  // block: 64 px * 256 k. thread t: px_loc = t/4, part = t%4 (8 k's per kb)
  const int P0 = blockIdx.x * 64;
  const int px_loc = threadIdx.x >> 2, part = threadIdx.x & 3;
  const int P = P0 + px_loc;
  const int n = P / kHW, hw = P % kHW;
  const int pt = px_loc >> 4, l = px_loc & 15;
  unsigned short* dst =
      xbi + ((size_t)(P0 / 16) + pt) * 4096 + l * 32 + part * 8;
  const float* xp = x + ((size_t)n * 240) * kHW + hw;
#pragma unroll
  for (int kb = 0; kb < 8; ++kb) {
    unsigned short v[8];
#pragma unroll
    for (int j = 0; j < 8; ++j) {
      const int c = kb * 32 + part * 8 + j;
      v[j] = (c < 240) ? f2b(xp[(size_t)c * kHW]) : (unsigned short)0;
    }
    *reinterpret_cast<uint4*>(dst + kb * 512) =
        *reinterpret_cast<const uint4*>(v);
  }
}

// ---- fused conv1(GEMM)+BN+ReLU -> LDS -> dw3x3+BN2+shuffle -> y2i ----------
__global__ __launch_bounds__(256) void conv1_dw_fused(
    const unsigned short* __restrict__ xbi, const float* __restrict__ scale1,
    const float* __restrict__ shift1, const float* __restrict__ w2,
    const float* __restrict__ scale2, const float* __restrict__ shift2,
    unsigned short* __restrict__ y2i) {
  const int h = blockIdx.x % 56;
  const int n = blockIdx.x / 56;
  // aligned 192-px window covering rows h-1..h+1 (halo)
  const int A0 = (h > 0) ? (((h - 1) * 56) & ~15) : 0;

  __shared__ unsigned short lds_y1[192 * 120];
  __shared__ float lds_w2[9 * 120];
  __shared__ float lds_s2[120], lds_h2[120];

  // stage dw weights / BN2
  for (int i = threadIdx.x; i < 9 * 120; i += 256) {
    const int tap = i / 120, c = i % 120;
    lds_w2[i] = w2[c * 9 + tap];
  }
  if (threadIdx.x < 120) {
    lds_s2[threadIdx.x] = scale2[threadIdx.x];
    lds_h2[threadIdx.x] = shift2[threadIdx.x];
  }

  // ---- conv1 phase: 12 ptiles x 120 ch, per wave m=3 ----
  const int lane = threadIdx.x & 63;
  const int wv = threadIdx.x >> 6;
  const int l15 = lane & 15, quad = lane >> 4;
  const size_t PT = (size_t)(n * kHW + A0) / 16 + wv * 3;

#pragma unroll
  for (int g = 0; g < 3; ++g) {
    f32x4 acc[3][3];
#pragma unroll
    for (int mt = 0; mt < 3; ++mt)
#pragma unroll
      for (int nt = 0; nt < 3; ++nt) acc[mt][nt] = (f32x4){0.f, 0.f, 0.f, 0.f};
#pragma unroll
    for (int kb = 0; kb < 4; ++kb) {
      const int kbi = 2 * g + kb;  // xbi kb index (window 64g..64g+128)
      bf16x8 A[3];
#pragma unroll
      for (int mt = 0; mt < 3; ++mt)
        A[mt] = ldg8(xbi + (PT + mt) * 4096 + kbi * 512 + l15 * 32 + quad * 8);
#pragma unroll
      for (int nt = 0; nt < 3; ++nt) {
        const bf16x8 B = ldg8(g_w1i + (((g * 4 + kb) * 48) + nt * 16 + l15) * 32 +
                              quad * 8);
#pragma unroll
        for (int mt = 0; mt < 3; ++mt) acc[mt][nt] = mfma16(A[mt], B, acc[mt][nt]);
      }
    }
    // epilogue: BN1+ReLU -> lds_y1[px_loc][c]
#pragma unroll
    for (int nt = 0; nt < 3; ++nt) {
      const int j = nt * 16 + l15;
      if (j < 40) {
        const int c = g * 40 + j;
        const float sc = scale1[c], sh = shift1[c];
#pragma unroll
        for (int mt = 0; mt < 3; ++mt) {
          const int pxb = wv * 48 + mt * 16 + quad * 4;
#pragma unroll
          for (int r = 0; r < 4; ++r) {
            float v = fmaf(acc[mt][nt][r], sc, sh);
            v = v > 0.f ? v : 0.f;
            lds_y1[(pxb + r) * 120 + c] = f2b(v);
          }
        }
      }
    }
  }
  __syncthreads();

  // ---- dw phase: out row h, 56 w x 120 c ----
  for (int idx = threadIdx.x; idx < 56 * 120; idx += 256) {
    const int c = idx % 120, w = idx / 120;
    float a = 0.f;
#pragma unroll
    for (int dy = 0; dy < 3; ++dy) {
      const int hh = h + dy - 1;
      if (hh < 0 || hh >= 56) continue;
#pragma unroll
      for (int dx = 0; dx < 3; ++dx) {
        const int ww = w + dx - 1;
        if (ww < 0 || ww >= 56) continue;
        const int pl = hh * 56 + ww - A0;
        a = fmaf(__uint_as_float((unsigned)lds_y1[pl * 120 + c] << 16),
                 lds_w2[(dy * 3 + dx) * 120 + c], a);
      }
    }
    const float v = fmaf(a, lds_s2[c], lds_h2[c]);
    const int cn = (c % 40) * 3 + c / 40;  // channel shuffle
    const int P = n * kHW + h * 56 + w;
    y2i[((size_t)(P >> 4)) * 2048 + (cn >> 5) * 512 + (P & 15) * 32 +
        (cn & 31)] = f2b(v);
  }
}

// ---- fused conv3 + BN3 + ReLU + shortcut + BN_sc (folded accumulator) ------
__global__ __launch_bounds__(256, 3) void conv3_sc_gemm(
    const unsigned short* __restrict__ xbi,
    const unsigned short* __restrict__ y2i, const float* __restrict__ scale3,
    const float* __restrict__ shift3, const float* __restrict__ ssc,
    const float* __restrict__ bsc, float* __restrict__ out) {
  const int pxb = blockIdx.x % 784;  // 128-px blocks
  const int cb = blockIdx.x / 784;   // 160-co block == conv3 group
  const int P0 = pxb * 128;
  const int lane = threadIdx.x & 63;
  const int wv = threadIdx.x >> 6;
  const int mh = wv & 1, nh = wv >> 1;  // wave: 64 px x 80 co
  const int l15 = lane & 15, quad = lane >> 4;
  const int cbase = cb * 160 + nh * 80;

  f32x4 acc[4][5];
#pragma unroll
  for (int mt = 0; mt < 4; ++mt)
#pragma unroll
    for (int nt = 0; nt < 5; ++nt) acc[mt][nt] = (f32x4){0.f, 0.f, 0.f, 0.f};

  const size_t PT = (size_t)(P0 / 16) + mh * 4;

  // ---- phase 1: conv3 GEMM (K-window = 2 kb at offset cb) ----
#pragma unroll
  for (int kb = 0; kb < 2; ++kb) {
    const int kbi = cb + kb;
    bf16x8 A[4];
#pragma unroll
    for (int mt = 0; mt < 4; ++mt)
      A[mt] = ldg8(y2i + (PT + mt) * 2048 + kbi * 512 + l15 * 32 + quad * 8);
#pragma unroll
    for (int nt = 0; nt < 5; ++nt) {
      const bf16x8 B =
          ldg8(g_w3i + ((kb * 480) + cbase + nt * 16 + l15) * 32 + quad * 8);
#pragma unroll
      for (int mt = 0; mt < 4; ++mt) acc[mt][nt] = mfma16(A[mt], B, acc[mt][nt]);
    }
  }

  // ---- fold: acc = (relu(bn3) + shift_sc) / scale_sc ----
#pragma unroll
  for (int nt = 0; nt < 5; ++nt) {
    const int co = cbase + nt * 16 + l15;
    const float s3 = scale3[co], h3 = shift3[co];
    const float is = 1.0f / ssc[co], h_ = bsc[co];
#pragma unroll
    for (int mt = 0; mt < 4; ++mt)
#pragma unroll
      for (int r = 0; r < 4; ++r) {
        float v3 = fmaf(acc[mt][nt][r], s3, h3);
        v3 = v3 > 0.f ? v3 : 0.f;
        acc[mt][nt][r] = (v3 + h_) * is;
      }
  }

  // ---- phase 2: shortcut GEMM (K=256, 240 real) ----
  for (int kb = 0; kb < 8; ++kb) {
    bf16x8 A[4];
#pragma unroll
    for (int mt = 0; mt < 4; ++mt)
      A[mt] = ldg8(xbi + (PT + mt) * 4096 + kb * 512 + l15 * 32 + quad * 8);
#pragma unroll
    for (int nt = 0; nt < 5; ++nt) {
      const bf16x8 B =
          ldg8(g_wsci + ((kb * 480) + cbase + nt * 16 + l15) * 32 + quad * 8);
#pragma unroll
      for (int mt = 0; mt < 4; ++mt) acc[mt][nt] = mfma16(A[mt], B, acc[mt][nt]);
    }
  }

  // ---- store: out = scale_sc * acc ----
#pragma unroll
  for (int mt = 0; mt < 4; ++mt) {
    const int P = P0 + mh * 64 + mt * 16 + quad * 4;
    const int n = P / kHW, hw = P % kHW;
    float* ob = out + (size_t)n * 480 * kHW + hw;
#pragma unroll
    for (int nt = 0; nt < 5; ++nt) {
      const int co = cbase + nt * 16 + l15;
      const float s_ = ssc[co];
      float4 r;
      float* rp = reinterpret_cast<float*>(&r);
#pragma unroll
      for (int r4 = 0; r4 < 4; ++r4) rp[r4] = s_ * acc[mt][nt][r4];
      *reinterpret_cast<float4*>(ob + (size_t)co * kHW) = r;
    }
  }
}

extern "C" void kernel_launch(void* const* d_in, const int* in_sizes, int n_in,
                              void* d_out, int out_size, void* d_ws,
                              size_t ws_size, hipStream_t stream) {
  const float* x = (const float*)d_in[0];
  const float* w1 = (const float*)d_in[1];
  const float* scale1 = (const float*)d_in[2];
  const float* shift1 = (const float*)d_in[3];
  const float* w2 = (const float*)d_in[4];
  const float* scale2 = (const float*)d_in[5];
  const float* shift2 = (const float*)d_in[6];
  const float* w3 = (const float*)d_in[7];
  const float* scale3 = (const float*)d_in[8];
  const float* shift3 = (const float*)d_in[9];
  const float* wsc = (const float*)d_in[10];
  const float* ssc = (const float*)d_in[11];
  const float* bsc = (const float*)d_in[12];
  float* out = (float*)d_out;

  unsigned short* xbi = (unsigned short*)d_ws;
  unsigned short* y2i = xbi + kXbiShorts;

  prep_weights<<<672, 256, 0, stream>>>(w1, wsc, w3);
  transpose_interleave<<<kNPx / 64, 256, 0, stream>>>(x, xbi);
  conv1_dw_fused<<<32 * 56, 256, 0, stream>>>(xbi, scale1, shift1, w2, scale2,
                                              shift2, y2i);
  conv3_sc_gemm<<<784 * 3, 256, 0, stream>>>(xbi, y2i, scale3, shift3, ssc,
                                             bsc, out);
}